// Round 9
// baseline (213.780 us; speedup 1.0000x reference)
//
#include <hip/hip_runtime.h>

#define NN 20000
#define NE 160000
#define NG 16
#define KP 1024            // padded feature dim
#define MT2 160            // max M strips of 128 in compact space
#define MPAD2 (MT2*128)    // 20480
#define NBLK 79            // ceil(20000/256)

typedef __attribute__((ext_vector_type(8))) short bf16x8;
typedef __attribute__((ext_vector_type(4))) float f32x4;

#define GAS __attribute__((address_space(1)))
#define LAS __attribute__((address_space(3)))

__device__ __forceinline__ unsigned short f2bf(float f) {
    unsigned int u = __float_as_uint(f);
    u += 0x7FFFu + ((u >> 16) & 1u);   // round-to-nearest-even
    return (unsigned short)(u >> 16);
}

__device__ __forceinline__ void gld_lds16(const char* g, char* l) {
    __builtin_amdgcn_global_load_lds((GAS void*)g, (LAS void*)l, 16, 0, 0);
}

// deg/cnt/cursor/logitsC/flags zeroed by hipMemsetAsync before this.
// Also probes the mask bit-format (int32 {0,1} / float32 {0,1.0f} / byte).
__global__ void deg_cnt_kernel(const int* __restrict__ ei, const float* __restrict__ ew,
                               float* deg, int* cnt, const void* __restrict__ mask,
                               int* flags) {
    const int e = blockIdx.x * blockDim.x + threadIdx.x;
    if (e < 5000) {
        const unsigned v = ((const unsigned*)mask)[e];
        if (v > 1u) atomicOr(&flags[0], 1);                      // not int32 {0,1}
        if (v != 0u && v != 0x3F800000u) atomicOr(&flags[1], 1); // not float32 {0,1.0f}
    }
    if (e >= NE) return;
    const int c = ei[NE + e];
    atomicAdd(&deg[c], ew[e]);
    atomicAdd(&cnt[c], 1);
}

// ---- parallel scan, phase 1: per-block sums (edge counts + mask), dinv, mask decode
__global__ __launch_bounds__(256) void partial_kernel(const int* __restrict__ cnt,
        const float* __restrict__ deg, const void* __restrict__ mask,
        const int* __restrict__ flags, int* __restrict__ mtmp,
        float* __restrict__ dinv, int* __restrict__ bcnt, int* __restrict__ bmsk) {
    const int b = blockIdx.x, t = threadIdx.x;
    const int i = b * 256 + t;
    const int f0 = flags[0], f1 = flags[1];
    int c = 0, mv = 0;
    if (i < NN) {
        c = cnt[i];
        dinv[i] = 1.0f / sqrtf(2.0f + deg[i]);   // self-loop weight 2 folded; > 0
        if (f0 == 0)      mv = ((const int*)mask)[i] != 0;
        else if (f1 == 0) mv = ((const unsigned*)mask)[i] != 0u;
        else              mv = ((const unsigned char*)mask)[i] != 0;
        mtmp[i] = mv;
    }
    __shared__ int sc[256], sm[256];
    sc[t] = c; sm[t] = mv;
    __syncthreads();
    for (int off = 128; off; off >>= 1) {
        if (t < off) { sc[t] += sc[t + off]; sm[t] += sm[t + off]; }
        __syncthreads();
    }
    if (t == 0) { bcnt[b] = sc[0]; bmsk[b] = sm[0]; }
}

// ---- phase 2: exclusive scan of the NBLK partials (one tiny block) + nm
__global__ __launch_bounds__(128) void scanp_kernel(int* __restrict__ bcnt,
        int* __restrict__ bmsk, int* __restrict__ nm) {
    const int t = threadIdx.x;
    __shared__ int sc[128], sm[128];
    const int c = (t < NBLK) ? bcnt[t] : 0;
    const int m = (t < NBLK) ? bmsk[t] : 0;
    sc[t] = c; sm[t] = m;
    __syncthreads();
    for (int off = 1; off < 128; off <<= 1) {
        const int uc = (t >= off) ? sc[t - off] : 0;
        const int um = (t >= off) ? sm[t - off] : 0;
        __syncthreads();
        sc[t] += uc; sm[t] += um;
        __syncthreads();
    }
    if (t < NBLK) { bcnt[t] = sc[t] - c; bmsk[t] = sm[t] - m; }   // exclusive
    if (t == NBLK - 1) nm[0] = sm[t];
}

// ---- phase 3: in-block scan + block offset -> offs, perm, bc
__global__ __launch_bounds__(256) void apply_kernel(const int* __restrict__ cnt,
        const int* __restrict__ mtmp, const int* __restrict__ bcnt,
        const int* __restrict__ bmsk, const int* __restrict__ batch,
        int* __restrict__ offs, int* __restrict__ perm, int* __restrict__ bc) {
    const int b = blockIdx.x, t = threadIdx.x;
    const int i = b * 256 + t;
    const int c  = (i < NN) ? cnt[i]  : 0;
    const int mv = (i < NN) ? mtmp[i] : 0;
    __shared__ int sc[256], sm[256];
    sc[t] = c; sm[t] = mv;
    __syncthreads();
    for (int off = 1; off < 256; off <<= 1) {
        const int uc = (t >= off) ? sc[t - off] : 0;
        const int um = (t >= off) ? sm[t - off] : 0;
        __syncthreads();
        sc[t] += uc; sm[t] += um;
        __syncthreads();
    }
    if (i < NN) {
        offs[i] = bcnt[b] + sc[t] - c;           // exclusive edge-count prefix
        if (mv) {
            const int pos = bmsk[b] + sm[t] - 1; // compact slot
            perm[pos] = i;
            bc[pos] = batch[i];
        }
    }
}

__global__ void scatter_kernel(const int* __restrict__ ei, const float* __restrict__ ew,
                               const float* __restrict__ dinv, const int* __restrict__ offs,
                               int* cursor, int* __restrict__ ssrc, float* __restrict__ snorm) {
    const int e = blockIdx.x * blockDim.x + threadIdx.x;
    if (e >= NE) return;
    const int r = ei[e], c = ei[NE + e];
    const int pos = atomicAdd(&cursor[c], 1);
    const int idx = offs[c] + pos;
    ssrc[idx] = r;
    snorm[idx] = dinv[r] * ew[e] * dinv[c];
}

// Axf = full first-layer aggregation incl. self-loop: Axf[i] = sum_e w_e x[src] + 2*dinv^2*x[i]
__global__ __launch_bounds__(256) void axf_kernel(const float* __restrict__ x,
        const int* __restrict__ ssrc, const float* __restrict__ snorm,
        const int* __restrict__ offs, const int* __restrict__ cnt,
        const float* __restrict__ dinv, float* __restrict__ Axf) {
    const int i = blockIdx.x * blockDim.x + threadIdx.x;
    if (i >= NN) return;
    float a0=0,a1=0,a2=0,a3=0,a4=0;
    const int s0 = offs[i], n = cnt[i];
    for (int e = s0; e < s0 + n; ++e) {
        const int r = ssrc[e];
        const float w = snorm[e];
        const float* xr = x + r * 5;
        a0 += w*xr[0]; a1 += w*xr[1]; a2 += w*xr[2]; a3 += w*xr[3]; a4 += w*xr[4];
    }
    const float wl = 2.0f * dinv[i] * dinv[i];
    const float* xi = x + i * 5;
    a0 += wl*xi[0]; a1 += wl*xi[1]; a2 += wl*xi[2]; a3 += wl*xi[3]; a4 += wl*xi[4];
    float* o = Axf + i * 5;
    o[0]=a0; o[1]=a1; o[2]=a2; o[3]=a3; o[4]=a4;
}

// W2t[n][k] = bf16(W2[k][n]) zero-padded to 1024x1024
__global__ __launch_bounds__(256) void w2t_kernel(const float* __restrict__ W2,
                                                  unsigned short* __restrict__ W2t) {
    __shared__ float tile[32][33];
    const int bw = blockIdx.x;
    const int n0 = (bw & 31) * 32;
    const int k0 = (bw >> 5) * 32;
    const int t = threadIdx.x;
    const int tx = t & 31, ty = t >> 5;        // 32 x 8
#pragma unroll
    for (int j = 0; j < 4; ++j) {
        const int k = k0 + ty + j * 8;
        const int n = n0 + tx;
        tile[ty + j * 8][tx] = (k < 1000 && n < 1000) ? W2[k * 1000 + n] : 0.0f;
    }
    __syncthreads();
#pragma unroll
    for (int j = 0; j < 4; ++j) {
        const int n = n0 + ty + j * 8;
        const int k = k0 + tx;
        W2t[(size_t)n * KP + k] = f2bf(tile[tx][ty + j * 8]);
    }
}

// G[j] = sum_e w_e * relu(Axf[src]@W1 + b1)  — h1 NEVER materialized. h1 rows are
// rank-5+bias (z = Axf[r]@W1 + b1), so recompute beats the 160 MB row-gather:
// each thread holds its 4 W1 columns in registers (coalesced float4 loads), per
// edge: 5 broadcast Axf reads + 20 FMA + relu + weighted acc. 8 compact dests
// per block; edge meta staged in LDS. Pad rows/cols written as zeros.
__global__ __launch_bounds__(256) void aggW1_kernel(const float* __restrict__ Axf,
        const float* __restrict__ W1, const float* __restrict__ b1,
        const int* __restrict__ ssrc, const float* __restrict__ snorm,
        const int* __restrict__ offs, const int* __restrict__ cnt,
        const float* __restrict__ dinv, const int* __restrict__ perm,
        const int* __restrict__ nm, unsigned short* __restrict__ G) {
    const int t = threadIdx.x;
    __shared__ int s_nm;
    if (t == 0) s_nm = nm[0];
    __syncthreads();
    const int nmv = s_nm;
    const int npad = (nmv + 127) & ~127;
    const int j0 = blockIdx.x * 8;
    if (j0 >= npad) return;

    const bool active = t < 250;
    const int c0 = active ? t * 4 : 1000 + (t - 250) * 4;   // pad threads own cols 1000..1023
    float w[5][4];
    float bb[4];
    if (active) {
#pragma unroll
        for (int f = 0; f < 5; ++f) {
            const float4 wv = *(const float4*)(W1 + f * 1000 + c0);
            w[f][0] = wv.x; w[f][1] = wv.y; w[f][2] = wv.z; w[f][3] = wv.w;
        }
        const float4 b4 = *(const float4*)(b1 + c0);
        bb[0] = b4.x; bb[1] = b4.y; bb[2] = b4.z; bb[3] = b4.w;
    } else {
#pragma unroll
        for (int f = 0; f < 5; ++f) { w[f][0]=0; w[f][1]=0; w[f][2]=0; w[f][3]=0; }
        bb[0]=0; bb[1]=0; bb[2]=0; bb[3]=0;
    }

    __shared__ int   se[64];
    __shared__ float sw[64];
    for (int jj = 0; jj < 8; ++jj) {
        const int j = j0 + jj;
        if (j >= npad) break;                     // uniform
        float acc0 = 0.f, acc1 = 0.f, acc2 = 0.f, acc3 = 0.f;
        if (j < nmv) {                            // uniform
            const int i = perm[j];
            const int s0 = offs[i], n = cnt[i];
            for (int base = 0; base < n; base += 64) {
                const int m = (n - base < 64) ? (n - base) : 64;
                __syncthreads();
                if (t < m) { se[t] = ssrc[s0 + base + t]; sw[t] = snorm[s0 + base + t]; }
                __syncthreads();
                for (int e = 0; e < m; ++e) {
                    const int r = se[e];
                    const float we = sw[e];
                    const float* axr = Axf + r * 5;
                    float z0 = bb[0], z1 = bb[1], z2 = bb[2], z3 = bb[3];
#pragma unroll
                    for (int f = 0; f < 5; ++f) {
                        const float a = axr[f];
                        z0 += a * w[f][0]; z1 += a * w[f][1];
                        z2 += a * w[f][2]; z3 += a * w[f][3];
                    }
                    acc0 += we * fmaxf(z0, 0.f); acc1 += we * fmaxf(z1, 0.f);
                    acc2 += we * fmaxf(z2, 0.f); acc3 += we * fmaxf(z3, 0.f);
                }
            }
            {   // self-loop
                const float wl = 2.0f * dinv[i] * dinv[i];
                const float* axi = Axf + i * 5;
                float z0 = bb[0], z1 = bb[1], z2 = bb[2], z3 = bb[3];
#pragma unroll
                for (int f = 0; f < 5; ++f) {
                    const float a = axi[f];
                    z0 += a * w[f][0]; z1 += a * w[f][1];
                    z2 += a * w[f][2]; z3 += a * w[f][3];
                }
                acc0 += wl * fmaxf(z0, 0.f); acc1 += wl * fmaxf(z1, 0.f);
                acc2 += wl * fmaxf(z2, 0.f); acc3 += wl * fmaxf(z3, 0.f);
            }
        }
        ushort4 pk;
        pk.x = f2bf(acc0); pk.y = f2bf(acc1); pk.z = f2bf(acc2); pk.w = f2bf(acc3);
        *(ushort4*)(G + (size_t)j * KP + c0) = pk;
    }
}

// logitsC[row] += sum_cols relu(G @ W2 + b2) * Wf over compact rows < nm.
// 128x128 tile / BK=32 / width-16 global_load_lds / XOR-swizzled LDS.
// tm=(bid>>6)*8+(bid&7), tn=(bid>>3)&7: id%8==tm%8 -> A-strip's 8 readers share
// an XCD (FETCH 163->33 MB measured R6). Blocks with tm >= active strips exit.
__global__ __launch_bounds__(256) void gemm_kernel(const unsigned short* __restrict__ A,
                                                   const unsigned short* __restrict__ B,
                                                   const float* __restrict__ b2,
                                                   const float* __restrict__ Wf,
                                                   const int* __restrict__ nm,
                                                   float* __restrict__ logitsC) {
    __shared__ unsigned short As[4096];  // 128 rows x 32 k (bf16) = 8 KB
    __shared__ unsigned short Bs[4096];
    const int tid = threadIdx.x;
    __shared__ int s_nm;
    if (tid == 0) s_nm = nm[0];
    __syncthreads();
    const int nmv = s_nm;
    const int mstrips = (nmv + 127) >> 7;
    const int bid = blockIdx.x;
    const int tm = (bid >> 6) * 8 + (bid & 7);   // 0..159, tm%8 == bid%8
    const int tn = (bid >> 3) & 7;
    if (tm >= mstrips) return;
    const int lane = tid & 63;
    const int wv = tid >> 6;
    const int wr = wv >> 1, wc = wv & 1;

    const int chunk = ((tid & 3) ^ ((tid >> 3) & 3)) * 16;
    const int rsub = tid >> 2;   // row 0..63 (+64 in round 1)
    const char* Ag = (const char*)(A + (size_t)(tm * 128 + rsub) * KP) + chunk;
    const char* Bg = (const char*)(B + (size_t)(tn * 128 + rsub) * KP) + chunk;
    char* AsW = (char*)As + wv * 1024;
    char* BsW = (char*)Bs + wv * 1024;

    f32x4 acc[4][4];
#pragma unroll
    for (int i = 0; i < 4; ++i)
#pragma unroll
        for (int j = 0; j < 4; ++j) acc[i][j] = (f32x4){0.f, 0.f, 0.f, 0.f};

    const int m = lane & 15;
    const int quad = lane >> 4;
    const int sw = quad ^ ((m >> 1) & 3);       // swizzled k-chunk slot
    const int aoff = (wr * 64 + m) * 64 + sw * 16;
    const int boff = (wc * 64 + m) * 64 + sw * 16;

    for (int kk = 0; kk < KP; kk += 32) {
        __syncthreads();
        const int kb = kk * 2;
        gld_lds16(Ag + kb,             AsW);
        gld_lds16(Ag + kb + 64 * 2048, AsW + 4096);
        gld_lds16(Bg + kb,             BsW);
        gld_lds16(Bg + kb + 64 * 2048, BsW + 4096);
        __syncthreads();
        bf16x8 af[4], bfv[4];
#pragma unroll
        for (int mt = 0; mt < 4; ++mt)
            af[mt] = *(const bf16x8*)((const char*)As + aoff + mt * 1024);
#pragma unroll
        for (int nt = 0; nt < 4; ++nt)
            bfv[nt] = *(const bf16x8*)((const char*)Bs + boff + nt * 1024);
#pragma unroll
        for (int mt = 0; mt < 4; ++mt)
#pragma unroll
            for (int nt = 0; nt < 4; ++nt)
                acc[mt][nt] = __builtin_amdgcn_mfma_f32_16x16x32_bf16(af[mt], bfv[nt], acc[mt][nt], 0, 0, 0);
    }

    // epilogue: C/D layout col = lane&15, row = quad*4 + reg
    const int col0 = tn * 128 + wc * 64 + m;
    const int row00 = tm * 128 + wr * 64 + quad * 4;
#pragma unroll
    for (int mt = 0; mt < 4; ++mt) {
        float ps0 = 0.f, ps1 = 0.f, ps2 = 0.f, ps3 = 0.f;
#pragma unroll
        for (int nt = 0; nt < 4; ++nt) {
            const int c = col0 + nt * 16;
            const float bbv = (c < 1000) ? b2[c] : 0.0f;
            const float wfv = (c < 1000) ? Wf[c] : 0.0f;
            ps0 += fmaxf(acc[mt][nt][0] + bbv, 0.f) * wfv;
            ps1 += fmaxf(acc[mt][nt][1] + bbv, 0.f) * wfv;
            ps2 += fmaxf(acc[mt][nt][2] + bbv, 0.f) * wfv;
            ps3 += fmaxf(acc[mt][nt][3] + bbv, 0.f) * wfv;
        }
#pragma unroll
        for (int msk = 1; msk < 16; msk <<= 1) {
            ps0 += __shfl_xor(ps0, msk);
            ps1 += __shfl_xor(ps1, msk);
            ps2 += __shfl_xor(ps2, msk);
            ps3 += __shfl_xor(ps3, msk);
        }
        if (m == 0) {
            const int row = row00 + mt * 16;
            if (row + 0 < nmv) atomicAdd(&logitsC[row + 0], ps0);
            if (row + 1 < nmv) atomicAdd(&logitsC[row + 1], ps1);
            if (row + 2 < nmv) atomicAdd(&logitsC[row + 2], ps2);
            if (row + 3 < nmv) atomicAdd(&logitsC[row + 3], ps3);
        }
    }
}

// segment softmax over compact (all-masked) logits; bc sorted -> binary search.
// out pre-zeroed by memset; only masked slots written via perm.
__global__ __launch_bounds__(256) void softmax_kernel(const float* __restrict__ logitsC,
        const int* __restrict__ perm, const int* __restrict__ bc,
        const int* __restrict__ nm, float* __restrict__ out) {
    const int g = blockIdx.x;
    const int t = threadIdx.x;
    __shared__ int s_lo, s_hi;
    __shared__ float red[4];
    __shared__ float sval;
    if (t == 0) {
        const int nmv = nm[0];
        int lo = 0, hi = nmv;
        while (lo < hi) { const int mid = (lo + hi) >> 1; if (bc[mid] < g) lo = mid + 1; else hi = mid; }
        s_lo = lo;
        int lo2 = lo, hi2 = nmv;
        while (lo2 < hi2) { const int mid = (lo2 + hi2) >> 1; if (bc[mid] < g + 1) lo2 = mid + 1; else hi2 = mid; }
        s_hi = lo2;
    }
    __syncthreads();
    const int lo = s_lo, hi = s_hi;
    float mx = -1e30f;
    for (int i = lo + t; i < hi; i += 256) mx = fmaxf(mx, logitsC[i]);
    for (int off = 32; off; off >>= 1) mx = fmaxf(mx, __shfl_down(mx, off));
    if ((t & 63) == 0) red[t >> 6] = mx;
    __syncthreads();
    if (t == 0) sval = fmaxf(fmaxf(red[0], red[1]), fmaxf(red[2], red[3]));
    __syncthreads();
    mx = sval;
    __syncthreads();
    float sm = 0.f;
    for (int i = lo + t; i < hi; i += 256) sm += expf(logitsC[i] - mx);
    for (int off = 32; off; off >>= 1) sm += __shfl_down(sm, off);
    if ((t & 63) == 0) red[t >> 6] = sm;
    __syncthreads();
    if (t == 0) sval = red[0] + red[1] + red[2] + red[3];
    __syncthreads();
    const float inv = 1.0f / fmaxf(sval, 1e-16f);
    for (int i = lo + t; i < hi; i += 256)
        out[perm[i]] = expf(logitsC[i] - mx) * inv;
}

extern "C" void kernel_launch(void* const* d_in, const int* in_sizes, int n_in,
                              void* d_out, int out_size, void* d_ws, size_t ws_size,
                              hipStream_t stream) {
    (void)in_sizes; (void)n_in; (void)ws_size;
    const float* x   = (const float*)d_in[0];
    const float* ew  = (const float*)d_in[1];
    const float* W1  = (const float*)d_in[2];
    const float* b1  = (const float*)d_in[3];
    const float* W2  = (const float*)d_in[4];
    const float* b2  = (const float*)d_in[5];
    const float* Wf  = (const float*)d_in[6];
    const int*   ei  = (const int*)d_in[8];
    const void*  mask  = d_in[9];
    const int*   batch = (const int*)d_in[10];
    float* out = (float*)d_out;

    char* p = (char*)d_ws;
    auto carve = [&](size_t bytes) { char* q = p; p += (bytes + 255) & ~(size_t)255; return q; };
    // zero-region (single hipMemsetAsync): deg, cnt, cursor, logitsC, flags
    char* zbase = p;
    float* deg     = (float*)carve(NN * 4);
    int*   cnt     = (int*)carve(NN * 4);
    int*   cursor  = (int*)carve(NN * 4);
    float* logitsC = (float*)carve(MPAD2 * 4);
    int*   flags   = (int*)carve(256);
    size_t zspan = (size_t)(p - zbase);
    int*   offs   = (int*)carve(NN * 4);
    float* dinv   = (float*)carve(NN * 4);
    int*   mtmp   = (int*)carve(NN * 4);
    int*   perm   = (int*)carve(NN * 4);
    int*   bc     = (int*)carve(NN * 4);
    int*   bcnt   = (int*)carve(NBLK * 4);
    int*   bmsk   = (int*)carve(NBLK * 4);
    int*   nmp    = (int*)carve(256);
    int*   ssrc   = (int*)carve(NE * 4);
    float* snorm  = (float*)carve(NE * 4);
    float* Axf    = (float*)carve(NN * 5 * 4);
    unsigned short* W2t = (unsigned short*)carve((size_t)KP * KP * 2);
    unsigned short* G   = (unsigned short*)carve((size_t)MPAD2 * KP * 2);

    hipMemsetAsync(zbase, 0, zspan, stream);
    hipMemsetAsync(out, 0, (size_t)out_size * 4, stream);
    hipLaunchKernelGGL(deg_cnt_kernel,  dim3(625),      dim3(256),  0, stream, ei, ew, deg, cnt, mask, flags);
    hipLaunchKernelGGL(partial_kernel,  dim3(NBLK),     dim3(256),  0, stream, cnt, deg, mask, flags, mtmp, dinv, bcnt, bmsk);
    hipLaunchKernelGGL(scanp_kernel,    dim3(1),        dim3(128),  0, stream, bcnt, bmsk, nmp);
    hipLaunchKernelGGL(apply_kernel,    dim3(NBLK),     dim3(256),  0, stream, cnt, mtmp, bcnt, bmsk, batch, offs, perm, bc);
    hipLaunchKernelGGL(scatter_kernel,  dim3(625),      dim3(256),  0, stream, ei, ew, dinv, offs, cursor, ssrc, snorm);
    hipLaunchKernelGGL(axf_kernel,      dim3(79),       dim3(256),  0, stream, x, ssrc, snorm, offs, cnt, dinv, Axf);
    hipLaunchKernelGGL(w2t_kernel,      dim3(1024),     dim3(256),  0, stream, W2, W2t);
    hipLaunchKernelGGL(aggW1_kernel,    dim3(MPAD2/8),  dim3(256),  0, stream, Axf, W1, b1, ssrc, snorm, offs, cnt, dinv, perm, nmp, G);
    hipLaunchKernelGGL(gemm_kernel,     dim3(MT2*8),    dim3(256),  0, stream, G, W2t, b2, Wf, nmp, logitsC);
    hipLaunchKernelGGL(softmax_kernel,  dim3(NG),       dim3(256),  0, stream, logitsC, perm, bc, nmp, out);
}

// Round 10
// 200.094 us; speedup vs baseline: 1.0684x; 1.0684x over previous
//
#include <hip/hip_runtime.h>

#define NN 20000
#define NE 160000
#define NG 16
#define KP 1024            // padded feature dim
#define MT2 160            // max M strips of 128 in compact space
#define MPAD2 (MT2*128)    // 20480
#define NBLK 79            // ceil(20000/256)

typedef __attribute__((ext_vector_type(8))) short bf16x8;
typedef __attribute__((ext_vector_type(4))) float f32x4;

#define GAS __attribute__((address_space(1)))
#define LAS __attribute__((address_space(3)))

__device__ __forceinline__ unsigned short f2bf(float f) {
    unsigned int u = __float_as_uint(f);
    u += 0x7FFFu + ((u >> 16) & 1u);   // round-to-nearest-even
    return (unsigned short)(u >> 16);
}

__device__ __forceinline__ void gld_lds16(const char* g, char* l) {
    __builtin_amdgcn_global_load_lds((GAS void*)g, (LAS void*)l, 16, 0, 0);
}

// deg/cnt/cursor/logitsC/flags zeroed by hipMemsetAsync before this.
// Also probes the mask bit-format (int32 {0,1} / float32 {0,1.0f} / byte).
__global__ void deg_cnt_kernel(const int* __restrict__ ei, const float* __restrict__ ew,
                               float* deg, int* cnt, const void* __restrict__ mask,
                               int* flags) {
    const int e = blockIdx.x * blockDim.x + threadIdx.x;
    if (e < 5000) {
        const unsigned v = ((const unsigned*)mask)[e];
        if (v > 1u) atomicOr(&flags[0], 1);                      // not int32 {0,1}
        if (v != 0u && v != 0x3F800000u) atomicOr(&flags[1], 1); // not float32 {0,1.0f}
    }
    if (e >= NE) return;
    const int c = ei[NE + e];
    atomicAdd(&deg[c], ew[e]);
    atomicAdd(&cnt[c], 1);
}

// blocks 0..NBLK-1: per-block sums (edge counts + mask), dinv, mask decode.
// blocks NBLK..NBLK+1023: W2t[n][k] = bf16(W2[k][n]) zero-padded to 1024x1024.
__global__ __launch_bounds__(256) void partial_w2t_kernel(const int* __restrict__ cnt,
        const float* __restrict__ deg, const void* __restrict__ mask,
        const int* __restrict__ flags, int* __restrict__ mtmp,
        float* __restrict__ dinv, int* __restrict__ bcnt, int* __restrict__ bmsk,
        const float* __restrict__ W2, unsigned short* __restrict__ W2t) {
    const int bid = blockIdx.x;
    const int t = threadIdx.x;
    if (bid < NBLK) {
        const int i = bid * 256 + t;
        const int f0 = flags[0], f1 = flags[1];
        int c = 0, mv = 0;
        if (i < NN) {
            c = cnt[i];
            dinv[i] = 1.0f / sqrtf(2.0f + deg[i]);   // self-loop weight 2 folded; > 0
            if (f0 == 0)      mv = ((const int*)mask)[i] != 0;
            else if (f1 == 0) mv = ((const unsigned*)mask)[i] != 0u;
            else              mv = ((const unsigned char*)mask)[i] != 0;
            mtmp[i] = mv;
        }
        __shared__ int sc[256], sm[256];
        sc[t] = c; sm[t] = mv;
        __syncthreads();
        for (int off = 128; off; off >>= 1) {
            if (t < off) { sc[t] += sc[t + off]; sm[t] += sm[t + off]; }
            __syncthreads();
        }
        if (t == 0) { bcnt[bid] = sc[0]; bmsk[bid] = sm[0]; }
    } else {
        __shared__ float tile[32][33];
        const int bw = bid - NBLK;
        const int n0 = (bw & 31) * 32;
        const int k0 = (bw >> 5) * 32;
        const int tx = t & 31, ty = t >> 5;        // 32 x 8
#pragma unroll
        for (int j = 0; j < 4; ++j) {
            const int k = k0 + ty + j * 8;
            const int n = n0 + tx;
            tile[ty + j * 8][tx] = (k < 1000 && n < 1000) ? W2[k * 1000 + n] : 0.0f;
        }
        __syncthreads();
#pragma unroll
        for (int j = 0; j < 4; ++j) {
            const int n = n0 + ty + j * 8;
            const int k = k0 + tx;
            W2t[(size_t)n * KP + k] = f2bf(tile[tx][ty + j * 8]);
        }
    }
}

// apply: re-scan the NBLK partials in-block (cheap, kills the scanp launch),
// then in-block scan + offsets -> offs, perm, bc; block 0 writes nm.
__global__ __launch_bounds__(256) void apply_kernel(const int* __restrict__ cnt,
        const int* __restrict__ mtmp, const int* __restrict__ bcnt,
        const int* __restrict__ bmsk, const int* __restrict__ batch,
        int* __restrict__ offs, int* __restrict__ perm, int* __restrict__ bc,
        int* __restrict__ nm) {
    const int b = blockIdx.x, t = threadIdx.x;
    __shared__ int pbc[128], pbm[128];
    if (t < 128) {
        pbc[t] = (t < NBLK) ? bcnt[t] : 0;
        pbm[t] = (t < NBLK) ? bmsk[t] : 0;
    }
    __syncthreads();
    for (int off = 1; off < 128; off <<= 1) {       // inclusive scan of partials
        int uc = 0, um = 0;
        if (t < 128 && t >= off) { uc = pbc[t - off]; um = pbm[t - off]; }
        __syncthreads();
        if (t < 128) { pbc[t] += uc; pbm[t] += um; }
        __syncthreads();
    }
    if (b == 0 && t == 0) nm[0] = pbm[NBLK - 1];
    const int bco = (b == 0) ? 0 : pbc[b - 1];      // exclusive block offsets
    const int bmo = (b == 0) ? 0 : pbm[b - 1];
    const int i = b * 256 + t;
    const int c  = (i < NN) ? cnt[i]  : 0;
    const int mv = (i < NN) ? mtmp[i] : 0;
    __shared__ int sc[256], sm[256];
    sc[t] = c; sm[t] = mv;
    __syncthreads();
    for (int off = 1; off < 256; off <<= 1) {
        const int uc = (t >= off) ? sc[t - off] : 0;
        const int um = (t >= off) ? sm[t - off] : 0;
        __syncthreads();
        sc[t] += uc; sm[t] += um;
        __syncthreads();
    }
    if (i < NN) {
        offs[i] = bco + sc[t] - c;                  // exclusive edge-count prefix
        if (mv) {
            const int pos = bmo + sm[t] - 1;        // compact slot
            perm[pos] = i;
            bc[pos] = batch[i];
        }
    }
}

__global__ void scatter_kernel(const int* __restrict__ ei, const float* __restrict__ ew,
                               const float* __restrict__ dinv, const int* __restrict__ offs,
                               int* cursor, int* __restrict__ ssrc, float* __restrict__ snorm) {
    const int e = blockIdx.x * blockDim.x + threadIdx.x;
    if (e >= NE) return;
    const int r = ei[e], c = ei[NE + e];
    const int pos = atomicAdd(&cursor[c], 1);
    const int idx = offs[c] + pos;
    ssrc[idx] = r;
    snorm[idx] = dinv[r] * ew[e] * dinv[c];
}

// Axf = full first-layer aggregation incl. self-loop
__global__ __launch_bounds__(256) void axf_kernel(const float* __restrict__ x,
        const int* __restrict__ ssrc, const float* __restrict__ snorm,
        const int* __restrict__ offs, const int* __restrict__ cnt,
        const float* __restrict__ dinv, float* __restrict__ Axf) {
    const int i = blockIdx.x * blockDim.x + threadIdx.x;
    if (i >= NN) return;
    float a0=0,a1=0,a2=0,a3=0,a4=0;
    const int s0 = offs[i], n = cnt[i];
    for (int e = s0; e < s0 + n; ++e) {
        const int r = ssrc[e];
        const float w = snorm[e];
        const float* xr = x + r * 5;
        a0 += w*xr[0]; a1 += w*xr[1]; a2 += w*xr[2]; a3 += w*xr[3]; a4 += w*xr[4];
    }
    const float wl = 2.0f * dinv[i] * dinv[i];
    const float* xi = x + i * 5;
    a0 += wl*xi[0]; a1 += wl*xi[1]; a2 += wl*xi[2]; a3 += wl*xi[3]; a4 += wl*xi[4];
    float* o = Axf + i * 5;
    o[0]=a0; o[1]=a1; o[2]=a2; o[3]=a3; o[4]=a4;
}

// G[j] = sum_e w_e * relu(Axf[src]@W1 + b1) — h1 never materialized (rank-5+bias
// recompute). R9 leak fixed: per 64-edge chunk, staging threads pull edge meta AND
// the source's 5 Axf floats into LDS (float4+float2 packing -> ds_read_b128/b64
// broadcasts in the compute loop), so no uniform global load sits in the serial
// edge loop. Self-loop folded in as pseudo-edge n. 8 compact dests per block.
__global__ __launch_bounds__(256) void aggW1_kernel(const float* __restrict__ Axf,
        const float* __restrict__ W1, const float* __restrict__ b1,
        const int* __restrict__ ssrc, const float* __restrict__ snorm,
        const int* __restrict__ offs, const int* __restrict__ cnt,
        const float* __restrict__ dinv, const int* __restrict__ perm,
        const int* __restrict__ nm, unsigned short* __restrict__ G) {
    const int t = threadIdx.x;
    __shared__ int s_nm;
    if (t == 0) s_nm = nm[0];
    __syncthreads();
    const int nmv = s_nm;
    const int npad = (nmv + 127) & ~127;
    const int j0 = blockIdx.x * 8;
    if (j0 >= npad) return;

    const bool active = t < 250;
    const int c0 = active ? t * 4 : 1000 + (t - 250) * 4;   // pad threads own cols 1000..1023
    float w[5][4];
    float bb[4];
    if (active) {
#pragma unroll
        for (int f = 0; f < 5; ++f) {
            const float4 wv = *(const float4*)(W1 + f * 1000 + c0);
            w[f][0] = wv.x; w[f][1] = wv.y; w[f][2] = wv.z; w[f][3] = wv.w;
        }
        const float4 b4 = *(const float4*)(b1 + c0);
        bb[0] = b4.x; bb[1] = b4.y; bb[2] = b4.z; bb[3] = b4.w;
    } else {
#pragma unroll
        for (int f = 0; f < 5; ++f) { w[f][0]=0; w[f][1]=0; w[f][2]=0; w[f][3]=0; }
        bb[0]=0; bb[1]=0; bb[2]=0; bb[3]=0;
    }

    __shared__ float4 sax4[64];   // Axf[src][0..3]
    __shared__ float2 sax2[64];   // {Axf[src][4], w_e}
    for (int jj = 0; jj < 8; ++jj) {
        const int j = j0 + jj;
        if (j >= npad) break;                     // uniform
        float acc0 = 0.f, acc1 = 0.f, acc2 = 0.f, acc3 = 0.f;
        if (j < nmv) {                            // uniform
            const int i = perm[j];
            const int s0 = offs[i], n = cnt[i];
            const int total = n + 1;              // + self-loop pseudo-edge
            for (int base = 0; base < total; base += 64) {
                const int m = (total - base < 64) ? (total - base) : 64;
                __syncthreads();
                if (t < m) {
                    const int idx = base + t;
                    int r; float we;
                    if (idx < n) { r = ssrc[s0 + idx]; we = snorm[s0 + idx]; }
                    else         { r = i; const float dv = dinv[i]; we = 2.0f * dv * dv; }
                    const float* axr = Axf + r * 5;
                    sax4[t] = make_float4(axr[0], axr[1], axr[2], axr[3]);
                    sax2[t] = make_float2(axr[4], we);
                }
                __syncthreads();
#pragma unroll 2
                for (int e = 0; e < m; ++e) {
                    const float4 a4 = sax4[e];
                    const float2 a2 = sax2[e];
                    float z0 = bb[0], z1 = bb[1], z2 = bb[2], z3 = bb[3];
                    z0 += a4.x*w[0][0]; z1 += a4.x*w[0][1]; z2 += a4.x*w[0][2]; z3 += a4.x*w[0][3];
                    z0 += a4.y*w[1][0]; z1 += a4.y*w[1][1]; z2 += a4.y*w[1][2]; z3 += a4.y*w[1][3];
                    z0 += a4.z*w[2][0]; z1 += a4.z*w[2][1]; z2 += a4.z*w[2][2]; z3 += a4.z*w[2][3];
                    z0 += a4.w*w[3][0]; z1 += a4.w*w[3][1]; z2 += a4.w*w[3][2]; z3 += a4.w*w[3][3];
                    z0 += a2.x*w[4][0]; z1 += a2.x*w[4][1]; z2 += a2.x*w[4][2]; z3 += a2.x*w[4][3];
                    const float we = a2.y;
                    acc0 += we * fmaxf(z0, 0.f); acc1 += we * fmaxf(z1, 0.f);
                    acc2 += we * fmaxf(z2, 0.f); acc3 += we * fmaxf(z3, 0.f);
                }
            }
        }
        ushort4 pk;
        pk.x = f2bf(acc0); pk.y = f2bf(acc1); pk.z = f2bf(acc2); pk.w = f2bf(acc3);
        *(ushort4*)(G + (size_t)j * KP + c0) = pk;
    }
}

// logitsC[row] += sum_cols relu(G @ W2 + b2) * Wf over compact rows < nm.
// 128x128 tile / BK=32 / width-16 global_load_lds / XOR-swizzled LDS.
// tm=(bid>>6)*8+(bid&7), tn=(bid>>3)&7: id%8==tm%8 -> A-strip's 8 readers share
// an XCD (FETCH 163->33 MB measured R6). Blocks with tm >= active strips exit.
__global__ __launch_bounds__(256) void gemm_kernel(const unsigned short* __restrict__ A,
                                                   const unsigned short* __restrict__ B,
                                                   const float* __restrict__ b2,
                                                   const float* __restrict__ Wf,
                                                   const int* __restrict__ nm,
                                                   float* __restrict__ logitsC) {
    __shared__ unsigned short As[4096];  // 128 rows x 32 k (bf16) = 8 KB
    __shared__ unsigned short Bs[4096];
    const int tid = threadIdx.x;
    __shared__ int s_nm;
    if (tid == 0) s_nm = nm[0];
    __syncthreads();
    const int nmv = s_nm;
    const int mstrips = (nmv + 127) >> 7;
    const int bid = blockIdx.x;
    const int tm = (bid >> 6) * 8 + (bid & 7);   // 0..159, tm%8 == bid%8
    const int tn = (bid >> 3) & 7;
    if (tm >= mstrips) return;
    const int lane = tid & 63;
    const int wv = tid >> 6;
    const int wr = wv >> 1, wc = wv & 1;

    const int chunk = ((tid & 3) ^ ((tid >> 3) & 3)) * 16;
    const int rsub = tid >> 2;   // row 0..63 (+64 in round 1)
    const char* Ag = (const char*)(A + (size_t)(tm * 128 + rsub) * KP) + chunk;
    const char* Bg = (const char*)(B + (size_t)(tn * 128 + rsub) * KP) + chunk;
    char* AsW = (char*)As + wv * 1024;
    char* BsW = (char*)Bs + wv * 1024;

    f32x4 acc[4][4];
#pragma unroll
    for (int i = 0; i < 4; ++i)
#pragma unroll
        for (int j = 0; j < 4; ++j) acc[i][j] = (f32x4){0.f, 0.f, 0.f, 0.f};

    const int m = lane & 15;
    const int quad = lane >> 4;
    const int sw = quad ^ ((m >> 1) & 3);       // swizzled k-chunk slot
    const int aoff = (wr * 64 + m) * 64 + sw * 16;
    const int boff = (wc * 64 + m) * 64 + sw * 16;

    for (int kk = 0; kk < KP; kk += 32) {
        __syncthreads();
        const int kb = kk * 2;
        gld_lds16(Ag + kb,             AsW);
        gld_lds16(Ag + kb + 64 * 2048, AsW + 4096);
        gld_lds16(Bg + kb,             BsW);
        gld_lds16(Bg + kb + 64 * 2048, BsW + 4096);
        __syncthreads();
        bf16x8 af[4], bfv[4];
#pragma unroll
        for (int mt = 0; mt < 4; ++mt)
            af[mt] = *(const bf16x8*)((const char*)As + aoff + mt * 1024);
#pragma unroll
        for (int nt = 0; nt < 4; ++nt)
            bfv[nt] = *(const bf16x8*)((const char*)Bs + boff + nt * 1024);
#pragma unroll
        for (int mt = 0; mt < 4; ++mt)
#pragma unroll
            for (int nt = 0; nt < 4; ++nt)
                acc[mt][nt] = __builtin_amdgcn_mfma_f32_16x16x32_bf16(af[mt], bfv[nt], acc[mt][nt], 0, 0, 0);
    }

    // epilogue: C/D layout col = lane&15, row = quad*4 + reg
    const int col0 = tn * 128 + wc * 64 + m;
    const int row00 = tm * 128 + wr * 64 + quad * 4;
#pragma unroll
    for (int mt = 0; mt < 4; ++mt) {
        float ps0 = 0.f, ps1 = 0.f, ps2 = 0.f, ps3 = 0.f;
#pragma unroll
        for (int nt = 0; nt < 4; ++nt) {
            const int c = col0 + nt * 16;
            const float bbv = (c < 1000) ? b2[c] : 0.0f;
            const float wfv = (c < 1000) ? Wf[c] : 0.0f;
            ps0 += fmaxf(acc[mt][nt][0] + bbv, 0.f) * wfv;
            ps1 += fmaxf(acc[mt][nt][1] + bbv, 0.f) * wfv;
            ps2 += fmaxf(acc[mt][nt][2] + bbv, 0.f) * wfv;
            ps3 += fmaxf(acc[mt][nt][3] + bbv, 0.f) * wfv;
        }
#pragma unroll
        for (int msk = 1; msk < 16; msk <<= 1) {
            ps0 += __shfl_xor(ps0, msk);
            ps1 += __shfl_xor(ps1, msk);
            ps2 += __shfl_xor(ps2, msk);
            ps3 += __shfl_xor(ps3, msk);
        }
        if (m == 0) {
            const int row = row00 + mt * 16;
            if (row + 0 < nmv) atomicAdd(&logitsC[row + 0], ps0);
            if (row + 1 < nmv) atomicAdd(&logitsC[row + 1], ps1);
            if (row + 2 < nmv) atomicAdd(&logitsC[row + 2], ps2);
            if (row + 3 < nmv) atomicAdd(&logitsC[row + 3], ps3);
        }
    }
}

// segment softmax over compact (all-masked) logits; bc sorted -> binary search.
// out pre-zeroed by memset; only masked slots written via perm.
__global__ __launch_bounds__(256) void softmax_kernel(const float* __restrict__ logitsC,
        const int* __restrict__ perm, const int* __restrict__ bc,
        const int* __restrict__ nm, float* __restrict__ out) {
    const int g = blockIdx.x;
    const int t = threadIdx.x;
    __shared__ int s_lo, s_hi;
    __shared__ float red[4];
    __shared__ float sval;
    if (t == 0) {
        const int nmv = nm[0];
        int lo = 0, hi = nmv;
        while (lo < hi) { const int mid = (lo + hi) >> 1; if (bc[mid] < g) lo = mid + 1; else hi = mid; }
        s_lo = lo;
        int lo2 = lo, hi2 = nmv;
        while (lo2 < hi2) { const int mid = (lo2 + hi2) >> 1; if (bc[mid] < g + 1) lo2 = mid + 1; else hi2 = mid; }
        s_hi = lo2;
    }
    __syncthreads();
    const int lo = s_lo, hi = s_hi;
    float mx = -1e30f;
    for (int i = lo + t; i < hi; i += 256) mx = fmaxf(mx, logitsC[i]);
    for (int off = 32; off; off >>= 1) mx = fmaxf(mx, __shfl_down(mx, off));
    if ((t & 63) == 0) red[t >> 6] = mx;
    __syncthreads();
    if (t == 0) sval = fmaxf(fmaxf(red[0], red[1]), fmaxf(red[2], red[3]));
    __syncthreads();
    mx = sval;
    __syncthreads();
    float sm = 0.f;
    for (int i = lo + t; i < hi; i += 256) sm += expf(logitsC[i] - mx);
    for (int off = 32; off; off >>= 1) sm += __shfl_down(sm, off);
    if ((t & 63) == 0) red[t >> 6] = sm;
    __syncthreads();
    if (t == 0) sval = red[0] + red[1] + red[2] + red[3];
    __syncthreads();
    const float inv = 1.0f / fmaxf(sval, 1e-16f);
    for (int i = lo + t; i < hi; i += 256)
        out[perm[i]] = expf(logitsC[i] - mx) * inv;
}

extern "C" void kernel_launch(void* const* d_in, const int* in_sizes, int n_in,
                              void* d_out, int out_size, void* d_ws, size_t ws_size,
                              hipStream_t stream) {
    (void)in_sizes; (void)n_in; (void)ws_size;
    const float* x   = (const float*)d_in[0];
    const float* ew  = (const float*)d_in[1];
    const float* W1  = (const float*)d_in[2];
    const float* b1  = (const float*)d_in[3];
    const float* W2  = (const float*)d_in[4];
    const float* b2  = (const float*)d_in[5];
    const float* Wf  = (const float*)d_in[6];
    const int*   ei  = (const int*)d_in[8];
    const void*  mask  = d_in[9];
    const int*   batch = (const int*)d_in[10];
    float* out = (float*)d_out;

    char* p = (char*)d_ws;
    auto carve = [&](size_t bytes) { char* q = p; p += (bytes + 255) & ~(size_t)255; return q; };
    // zero-region (single hipMemsetAsync): deg, cnt, cursor, logitsC, flags
    char* zbase = p;
    float* deg     = (float*)carve(NN * 4);
    int*   cnt     = (int*)carve(NN * 4);
    int*   cursor  = (int*)carve(NN * 4);
    float* logitsC = (float*)carve(MPAD2 * 4);
    int*   flags   = (int*)carve(256);
    size_t zspan = (size_t)(p - zbase);
    int*   offs   = (int*)carve(NN * 4);
    float* dinv   = (float*)carve(NN * 4);
    int*   mtmp   = (int*)carve(NN * 4);
    int*   perm   = (int*)carve(NN * 4);
    int*   bc     = (int*)carve(NN * 4);
    int*   bcnt   = (int*)carve(NBLK * 4);
    int*   bmsk   = (int*)carve(NBLK * 4);
    int*   nmp    = (int*)carve(256);
    int*   ssrc   = (int*)carve(NE * 4);
    float* snorm  = (float*)carve(NE * 4);
    float* Axf    = (float*)carve(NN * 5 * 4);
    unsigned short* W2t = (unsigned short*)carve((size_t)KP * KP * 2);
    unsigned short* G   = (unsigned short*)carve((size_t)MPAD2 * KP * 2);

    hipMemsetAsync(zbase, 0, zspan, stream);
    hipMemsetAsync(out, 0, (size_t)out_size * 4, stream);
    hipLaunchKernelGGL(deg_cnt_kernel,    dim3(625),       dim3(256), 0, stream, ei, ew, deg, cnt, mask, flags);
    hipLaunchKernelGGL(partial_w2t_kernel, dim3(NBLK+1024), dim3(256), 0, stream, cnt, deg, mask, flags, mtmp, dinv, bcnt, bmsk, W2, W2t);
    hipLaunchKernelGGL(apply_kernel,      dim3(NBLK),      dim3(256), 0, stream, cnt, mtmp, bcnt, bmsk, batch, offs, perm, bc, nmp);
    hipLaunchKernelGGL(scatter_kernel,    dim3(625),       dim3(256), 0, stream, ei, ew, dinv, offs, cursor, ssrc, snorm);
    hipLaunchKernelGGL(axf_kernel,        dim3(79),        dim3(256), 0, stream, x, ssrc, snorm, offs, cnt, dinv, Axf);
    hipLaunchKernelGGL(aggW1_kernel,      dim3(MPAD2/8),   dim3(256), 0, stream, Axf, W1, b1, ssrc, snorm, offs, cnt, dinv, perm, nmp, G);
    hipLaunchKernelGGL(gemm_kernel,       dim3(MT2*8),     dim3(256), 0, stream, G, W2t, b2, Wf, nmp, logitsC);
    hipLaunchKernelGGL(softmax_kernel,    dim3(NG),        dim3(256), 0, stream, logitsC, perm, bc, nmp, out);
}

// Round 11
// 198.527 us; speedup vs baseline: 1.0768x; 1.0079x over previous
//
#include <hip/hip_runtime.h>

#define NN 20000
#define NE 160000
#define NG 16
#define KP 1024            // padded feature dim
#define MT2 160            // max M strips of 128 in compact space
#define MPAD2 (MT2*128)    // 20480
#define NBLK 79            // ceil(20000/256)

typedef __attribute__((ext_vector_type(8))) short bf16x8;
typedef __attribute__((ext_vector_type(4))) float f32x4;

#define GAS __attribute__((address_space(1)))
#define LAS __attribute__((address_space(3)))

__device__ __forceinline__ unsigned short f2bf(float f) {
    unsigned int u = __float_as_uint(f);
    u += 0x7FFFu + ((u >> 16) & 1u);   // round-to-nearest-even
    return (unsigned short)(u >> 16);
}

__device__ __forceinline__ void gld_lds16(const char* g, char* l) {
    __builtin_amdgcn_global_load_lds((GAS void*)g, (LAS void*)l, 16, 0, 0);
}

// deg/cnt/flags zeroed by hipMemsetAsync before this.
// Also probes the mask bit-format (int32 {0,1} / float32 {0,1.0f} / byte).
__global__ void deg_cnt_kernel(const int* __restrict__ ei, const float* __restrict__ ew,
                               float* deg, int* cnt, const void* __restrict__ mask,
                               int* flags) {
    const int e = blockIdx.x * blockDim.x + threadIdx.x;
    if (e < 5000) {
        const unsigned v = ((const unsigned*)mask)[e];
        if (v > 1u) atomicOr(&flags[0], 1);                      // not int32 {0,1}
        if (v != 0u && v != 0x3F800000u) atomicOr(&flags[1], 1); // not float32 {0,1.0f}
    }
    if (e >= NE) return;
    const int c = ei[NE + e];
    atomicAdd(&deg[c], ew[e]);
    atomicAdd(&cnt[c], 1);
}

// blocks 0..NBLK-1: per-block sums (edge counts + mask), dinv, mask decode.
// blocks NBLK..NBLK+1023: W2t[n][k] = bf16(W2[k][n]) zero-padded, + zero logitsC.
__global__ __launch_bounds__(256) void partial_w2t_kernel(const int* __restrict__ cnt,
        const float* __restrict__ deg, const void* __restrict__ mask,
        const int* __restrict__ flags, int* __restrict__ mtmp,
        float* __restrict__ dinv, int* __restrict__ bcnt, int* __restrict__ bmsk,
        const float* __restrict__ W2, unsigned short* __restrict__ W2t,
        float* __restrict__ logitsC) {
    const int bid = blockIdx.x;
    const int t = threadIdx.x;
    if (bid < NBLK) {
        const int i = bid * 256 + t;
        const int f0 = flags[0], f1 = flags[1];
        int c = 0, mv = 0;
        if (i < NN) {
            c = cnt[i];
            dinv[i] = 1.0f / sqrtf(2.0f + deg[i]);   // self-loop weight 2 folded; > 0
            if (f0 == 0)      mv = ((const int*)mask)[i] != 0;
            else if (f1 == 0) mv = ((const unsigned*)mask)[i] != 0u;
            else              mv = ((const unsigned char*)mask)[i] != 0;
            mtmp[i] = mv;
        }
        __shared__ int sc[256], sm[256];
        sc[t] = c; sm[t] = mv;
        __syncthreads();
        for (int off = 128; off; off >>= 1) {
            if (t < off) { sc[t] += sc[t + off]; sm[t] += sm[t + off]; }
            __syncthreads();
        }
        if (t == 0) { bcnt[bid] = sc[0]; bmsk[bid] = sm[0]; }
    } else {
        __shared__ float tile[32][33];
        const int bw = bid - NBLK;
        if (t < 20) logitsC[bw * 20 + t] = 0.0f;   // 1024*20 == 20480 == MPAD2
        const int n0 = (bw & 31) * 32;
        const int k0 = (bw >> 5) * 32;
        const int tx = t & 31, ty = t >> 5;        // 32 x 8
#pragma unroll
        for (int j = 0; j < 4; ++j) {
            const int k = k0 + ty + j * 8;
            const int n = n0 + tx;
            tile[ty + j * 8][tx] = (k < 1000 && n < 1000) ? W2[k * 1000 + n] : 0.0f;
        }
        __syncthreads();
#pragma unroll
        for (int j = 0; j < 4; ++j) {
            const int n = n0 + ty + j * 8;
            const int k = k0 + tx;
            W2t[(size_t)n * KP + k] = f2bf(tile[tx][ty + j * 8]);
        }
    }
}

// apply: re-scan the NBLK partials in-block, then in-block scan + offsets ->
// offs, perm, bc; block 0 writes nm. Also zeroes cursor (pre-scatter) and
// out (pre-softmax; unmasked slots must be 0).
__global__ __launch_bounds__(256) void apply_kernel(const int* __restrict__ cnt,
        const int* __restrict__ mtmp, const int* __restrict__ bcnt,
        const int* __restrict__ bmsk, const int* __restrict__ batch,
        int* __restrict__ offs, int* __restrict__ perm, int* __restrict__ bc,
        int* __restrict__ nm, int* __restrict__ cursor, float* __restrict__ out) {
    const int b = blockIdx.x, t = threadIdx.x;
    __shared__ int pbc[128], pbm[128];
    if (t < 128) {
        pbc[t] = (t < NBLK) ? bcnt[t] : 0;
        pbm[t] = (t < NBLK) ? bmsk[t] : 0;
    }
    __syncthreads();
    for (int off = 1; off < 128; off <<= 1) {       // inclusive scan of partials
        int uc = 0, um = 0;
        if (t < 128 && t >= off) { uc = pbc[t - off]; um = pbm[t - off]; }
        __syncthreads();
        if (t < 128) { pbc[t] += uc; pbm[t] += um; }
        __syncthreads();
    }
    if (b == 0 && t == 0) nm[0] = pbm[NBLK - 1];
    const int bco = (b == 0) ? 0 : pbc[b - 1];      // exclusive block offsets
    const int bmo = (b == 0) ? 0 : pbm[b - 1];
    const int i = b * 256 + t;
    const int c  = (i < NN) ? cnt[i]  : 0;
    const int mv = (i < NN) ? mtmp[i] : 0;
    __shared__ int sc[256], sm[256];
    sc[t] = c; sm[t] = mv;
    __syncthreads();
    for (int off = 1; off < 256; off <<= 1) {
        const int uc = (t >= off) ? sc[t - off] : 0;
        const int um = (t >= off) ? sm[t - off] : 0;
        __syncthreads();
        sc[t] += uc; sm[t] += um;
        __syncthreads();
    }
    if (i < NN) {
        cursor[i] = 0;
        out[i] = 0.0f;
        offs[i] = bco + sc[t] - c;                  // exclusive edge-count prefix
        if (mv) {
            const int pos = bmo + sm[t] - 1;        // compact slot
            perm[pos] = i;
            bc[pos] = batch[i];
        }
    }
}

__global__ void scatter_kernel(const int* __restrict__ ei, const float* __restrict__ ew,
                               const float* __restrict__ dinv, const int* __restrict__ offs,
                               int* cursor, int* __restrict__ ssrc, float* __restrict__ snorm) {
    const int e = blockIdx.x * blockDim.x + threadIdx.x;
    if (e >= NE) return;
    const int r = ei[e], c = ei[NE + e];
    const int pos = atomicAdd(&cursor[c], 1);
    const int idx = offs[c] + pos;
    ssrc[idx] = r;
    snorm[idx] = dinv[r] * ew[e] * dinv[c];
}

// Axf = full first-layer aggregation incl. self-loop
__global__ __launch_bounds__(256) void axf_kernel(const float* __restrict__ x,
        const int* __restrict__ ssrc, const float* __restrict__ snorm,
        const int* __restrict__ offs, const int* __restrict__ cnt,
        const float* __restrict__ dinv, float* __restrict__ Axf) {
    const int i = blockIdx.x * blockDim.x + threadIdx.x;
    if (i >= NN) return;
    float a0=0,a1=0,a2=0,a3=0,a4=0;
    const int s0 = offs[i], n = cnt[i];
    for (int e = s0; e < s0 + n; ++e) {
        const int r = ssrc[e];
        const float w = snorm[e];
        const float* xr = x + r * 5;
        a0 += w*xr[0]; a1 += w*xr[1]; a2 += w*xr[2]; a3 += w*xr[3]; a4 += w*xr[4];
    }
    const float wl = 2.0f * dinv[i] * dinv[i];
    const float* xi = x + i * 5;
    a0 += wl*xi[0]; a1 += wl*xi[1]; a2 += wl*xi[2]; a3 += wl*xi[3]; a4 += wl*xi[4];
    float* o = Axf + i * 5;
    o[0]=a0; o[1]=a1; o[2]=a2; o[3]=a3; o[4]=a4;
}

// G[j] = sum_e w_e * relu(Axf[src]@W1 + b1) — h1 never materialized. BARRIER-FREE:
// each dest j is owned by a wave PAIR (wave handles 512 cols = 8/lane); per
// 64-edge chunk each lane pre-loads one edge's meta + 5 Axf floats in parallel,
// then the wave broadcasts edge e's values via __shfl (uniform index ->
// v_readlane/SGPR operands). No LDS, no __syncthreads, 4 independent waves/block.
// Self-loop folded as pseudo-edge n. Pad rows/cols written as zeros.
__global__ __launch_bounds__(256) void aggW1_kernel(const float* __restrict__ Axf,
        const float* __restrict__ W1, const float* __restrict__ b1,
        const int* __restrict__ ssrc, const float* __restrict__ snorm,
        const int* __restrict__ offs, const int* __restrict__ cnt,
        const float* __restrict__ dinv, const int* __restrict__ perm,
        const int* __restrict__ nm, unsigned short* __restrict__ G) {
    const int tid = threadIdx.x;
    const int wv = tid >> 6;
    const int lane = tid & 63;
    const int half = wv & 1;
    const int j = blockIdx.x * 2 + (wv >> 1);
    const int nmv = nm[0];
    const int npad = (nmv + 127) & ~127;
    if (j >= npad) return;        // wave-uniform (no barriers in this kernel)

    const int c0 = half * 512 + lane * 8;
    float w1r[5][8], bbr[8];
#pragma unroll
    for (int q = 0; q < 2; ++q) {
        const int c = c0 + q * 4;
        const bool v = (c <= 996);    // 1000 % 4 == 0: quads are all-valid or all-pad
#pragma unroll
        for (int f = 0; f < 5; ++f) {
            const float4 w4 = v ? *(const float4*)(W1 + f * 1000 + c)
                                : make_float4(0.f, 0.f, 0.f, 0.f);
            w1r[f][q*4+0] = w4.x; w1r[f][q*4+1] = w4.y;
            w1r[f][q*4+2] = w4.z; w1r[f][q*4+3] = w4.w;
        }
        const float4 b4 = v ? *(const float4*)(b1 + c) : make_float4(0.f, 0.f, 0.f, 0.f);
        bbr[q*4+0] = b4.x; bbr[q*4+1] = b4.y; bbr[q*4+2] = b4.z; bbr[q*4+3] = b4.w;
    }
    float acc[8];
#pragma unroll
    for (int k = 0; k < 8; ++k) acc[k] = 0.f;

    if (j < nmv) {
        const int i = perm[j];
        const int s0 = offs[i], n = cnt[i];
        const int total = n + 1;            // + self-loop pseudo-edge
        for (int base = 0; base < total; base += 64) {
            const int m = (total - base < 64) ? (total - base) : 64;
            float a0=0.f, a1=0.f, a2=0.f, a3=0.f, a4=0.f, we=0.f;
            if (lane < m) {
                const int idx = base + lane;
                int r;
                if (idx < n) { r = ssrc[s0 + idx]; we = snorm[s0 + idx]; }
                else         { r = i; const float dv = dinv[i]; we = 2.0f * dv * dv; }
                const float* axr = Axf + r * 5;
                a0 = axr[0]; a1 = axr[1]; a2 = axr[2]; a3 = axr[3]; a4 = axr[4];
            }
#pragma unroll 2
            for (int e = 0; e < m; ++e) {
                const float s0v = __shfl(a0, e);
                const float s1v = __shfl(a1, e);
                const float s2v = __shfl(a2, e);
                const float s3v = __shfl(a3, e);
                const float s4v = __shfl(a4, e);
                const float swv = __shfl(we, e);
#pragma unroll
                for (int k = 0; k < 8; ++k) {
                    const float z = bbr[k] + s0v * w1r[0][k] + s1v * w1r[1][k]
                                  + s2v * w1r[2][k] + s3v * w1r[3][k] + s4v * w1r[4][k];
                    acc[k] += swv * fmaxf(z, 0.f);
                }
            }
        }
    }
    bf16x8 pk;
#pragma unroll
    for (int k = 0; k < 8; ++k) pk[k] = (short)f2bf(acc[k]);
    *(bf16x8*)(G + (size_t)j * KP + c0) = pk;
}

// logitsC[row] += sum_cols relu(G @ W2 + b2) * Wf over compact rows < nm.
// 128x128 tile / BK=32 / width-16 global_load_lds / XOR-swizzled LDS.
// tm=(bid>>6)*8+(bid&7), tn=(bid>>3)&7: id%8==tm%8 -> A-strip's 8 readers share
// an XCD (FETCH 163->33 MB measured R6). Blocks with tm >= active strips exit.
__global__ __launch_bounds__(256) void gemm_kernel(const unsigned short* __restrict__ A,
                                                   const unsigned short* __restrict__ B,
                                                   const float* __restrict__ b2,
                                                   const float* __restrict__ Wf,
                                                   const int* __restrict__ nm,
                                                   float* __restrict__ logitsC) {
    __shared__ unsigned short As[4096];  // 128 rows x 32 k (bf16) = 8 KB
    __shared__ unsigned short Bs[4096];
    const int tid = threadIdx.x;
    __shared__ int s_nm;
    if (tid == 0) s_nm = nm[0];
    __syncthreads();
    const int nmv = s_nm;
    const int mstrips = (nmv + 127) >> 7;
    const int bid = blockIdx.x;
    const int tm = (bid >> 6) * 8 + (bid & 7);   // 0..159, tm%8 == bid%8
    const int tn = (bid >> 3) & 7;
    if (tm >= mstrips) return;
    const int lane = tid & 63;
    const int wv = tid >> 6;
    const int wr = wv >> 1, wc = wv & 1;

    const int chunk = ((tid & 3) ^ ((tid >> 3) & 3)) * 16;
    const int rsub = tid >> 2;   // row 0..63 (+64 in round 1)
    const char* Ag = (const char*)(A + (size_t)(tm * 128 + rsub) * KP) + chunk;
    const char* Bg = (const char*)(B + (size_t)(tn * 128 + rsub) * KP) + chunk;
    char* AsW = (char*)As + wv * 1024;
    char* BsW = (char*)Bs + wv * 1024;

    f32x4 acc[4][4];
#pragma unroll
    for (int i = 0; i < 4; ++i)
#pragma unroll
        for (int j = 0; j < 4; ++j) acc[i][j] = (f32x4){0.f, 0.f, 0.f, 0.f};

    const int m = lane & 15;
    const int quad = lane >> 4;
    const int sw = quad ^ ((m >> 1) & 3);       // swizzled k-chunk slot
    const int aoff = (wr * 64 + m) * 64 + sw * 16;
    const int boff = (wc * 64 + m) * 64 + sw * 16;

    for (int kk = 0; kk < KP; kk += 32) {
        __syncthreads();
        const int kb = kk * 2;
        gld_lds16(Ag + kb,             AsW);
        gld_lds16(Ag + kb + 64 * 2048, AsW + 4096);
        gld_lds16(Bg + kb,             BsW);
        gld_lds16(Bg + kb + 64 * 2048, BsW + 4096);
        __syncthreads();
        bf16x8 af[4], bfv[4];
#pragma unroll
        for (int mt = 0; mt < 4; ++mt)
            af[mt] = *(const bf16x8*)((const char*)As + aoff + mt * 1024);
#pragma unroll
        for (int nt = 0; nt < 4; ++nt)
            bfv[nt] = *(const bf16x8*)((const char*)Bs + boff + nt * 1024);
#pragma unroll
        for (int mt = 0; mt < 4; ++mt)
#pragma unroll
            for (int nt = 0; nt < 4; ++nt)
                acc[mt][nt] = __builtin_amdgcn_mfma_f32_16x16x32_bf16(af[mt], bfv[nt], acc[mt][nt], 0, 0, 0);
    }

    // epilogue: C/D layout col = lane&15, row = quad*4 + reg
    const int col0 = tn * 128 + wc * 64 + m;
    const int row00 = tm * 128 + wr * 64 + quad * 4;
#pragma unroll
    for (int mt = 0; mt < 4; ++mt) {
        float ps0 = 0.f, ps1 = 0.f, ps2 = 0.f, ps3 = 0.f;
#pragma unroll
        for (int nt = 0; nt < 4; ++nt) {
            const int c = col0 + nt * 16;
            const float bbv = (c < 1000) ? b2[c] : 0.0f;
            const float wfv = (c < 1000) ? Wf[c] : 0.0f;
            ps0 += fmaxf(acc[mt][nt][0] + bbv, 0.f) * wfv;
            ps1 += fmaxf(acc[mt][nt][1] + bbv, 0.f) * wfv;
            ps2 += fmaxf(acc[mt][nt][2] + bbv, 0.f) * wfv;
            ps3 += fmaxf(acc[mt][nt][3] + bbv, 0.f) * wfv;
        }
#pragma unroll
        for (int msk = 1; msk < 16; msk <<= 1) {
            ps0 += __shfl_xor(ps0, msk);
            ps1 += __shfl_xor(ps1, msk);
            ps2 += __shfl_xor(ps2, msk);
            ps3 += __shfl_xor(ps3, msk);
        }
        if (m == 0) {
            const int row = row00 + mt * 16;
            if (row + 0 < nmv) atomicAdd(&logitsC[row + 0], ps0);
            if (row + 1 < nmv) atomicAdd(&logitsC[row + 1], ps1);
            if (row + 2 < nmv) atomicAdd(&logitsC[row + 2], ps2);
            if (row + 3 < nmv) atomicAdd(&logitsC[row + 3], ps3);
        }
    }
}

// segment softmax over compact (all-masked) logits; bc sorted -> binary search.
// out pre-zeroed by apply_kernel; only masked slots written via perm.
__global__ __launch_bounds__(256) void softmax_kernel(const float* __restrict__ logitsC,
        const int* __restrict__ perm, const int* __restrict__ bc,
        const int* __restrict__ nm, float* __restrict__ out) {
    const int g = blockIdx.x;
    const int t = threadIdx.x;
    __shared__ int s_lo, s_hi;
    __shared__ float red[4];
    __shared__ float sval;
    if (t == 0) {
        const int nmv = nm[0];
        int lo = 0, hi = nmv;
        while (lo < hi) { const int mid = (lo + hi) >> 1; if (bc[mid] < g) lo = mid + 1; else hi = mid; }
        s_lo = lo;
        int lo2 = lo, hi2 = nmv;
        while (lo2 < hi2) { const int mid = (lo2 + hi2) >> 1; if (bc[mid] < g + 1) lo2 = mid + 1; else hi2 = mid; }
        s_hi = lo2;
    }
    __syncthreads();
    const int lo = s_lo, hi = s_hi;
    float mx = -1e30f;
    for (int i = lo + t; i < hi; i += 256) mx = fmaxf(mx, logitsC[i]);
    for (int off = 32; off; off >>= 1) mx = fmaxf(mx, __shfl_down(mx, off));
    if ((t & 63) == 0) red[t >> 6] = mx;
    __syncthreads();
    if (t == 0) sval = fmaxf(fmaxf(red[0], red[1]), fmaxf(red[2], red[3]));
    __syncthreads();
    mx = sval;
    __syncthreads();
    float sm = 0.f;
    for (int i = lo + t; i < hi; i += 256) sm += expf(logitsC[i] - mx);
    for (int off = 32; off; off >>= 1) sm += __shfl_down(sm, off);
    if ((t & 63) == 0) red[t >> 6] = sm;
    __syncthreads();
    if (t == 0) sval = red[0] + red[1] + red[2] + red[3];
    __syncthreads();
    const float inv = 1.0f / fmaxf(sval, 1e-16f);
    for (int i = lo + t; i < hi; i += 256)
        out[perm[i]] = expf(logitsC[i] - mx) * inv;
}

extern "C" void kernel_launch(void* const* d_in, const int* in_sizes, int n_in,
                              void* d_out, int out_size, void* d_ws, size_t ws_size,
                              hipStream_t stream) {
    (void)in_sizes; (void)n_in; (void)out_size; (void)ws_size;
    const float* x   = (const float*)d_in[0];
    const float* ew  = (const float*)d_in[1];
    const float* W1  = (const float*)d_in[2];
    const float* b1  = (const float*)d_in[3];
    const float* W2  = (const float*)d_in[4];
    const float* b2  = (const float*)d_in[5];
    const float* Wf  = (const float*)d_in[6];
    const int*   ei  = (const int*)d_in[8];
    const void*  mask  = d_in[9];
    const int*   batch = (const int*)d_in[10];
    float* out = (float*)d_out;

    char* p = (char*)d_ws;
    auto carve = [&](size_t bytes) { char* q = p; p += (bytes + 255) & ~(size_t)255; return q; };
    // zero-region (single hipMemsetAsync): deg, cnt, flags only
    char* zbase = p;
    float* deg     = (float*)carve(NN * 4);
    int*   cnt     = (int*)carve(NN * 4);
    int*   flags   = (int*)carve(256);
    size_t zspan = (size_t)(p - zbase);
    int*   cursor  = (int*)carve(NN * 4);
    float* logitsC = (float*)carve(MPAD2 * 4);
    int*   offs   = (int*)carve(NN * 4);
    float* dinv   = (float*)carve(NN * 4);
    int*   mtmp   = (int*)carve(NN * 4);
    int*   perm   = (int*)carve(NN * 4);
    int*   bc     = (int*)carve(NN * 4);
    int*   bcnt   = (int*)carve(NBLK * 4);
    int*   bmsk   = (int*)carve(NBLK * 4);
    int*   nmp    = (int*)carve(256);
    int*   ssrc   = (int*)carve(NE * 4);
    float* snorm  = (float*)carve(NE * 4);
    float* Axf    = (float*)carve(NN * 5 * 4);
    unsigned short* W2t = (unsigned short*)carve((size_t)KP * KP * 2);
    unsigned short* G   = (unsigned short*)carve((size_t)MPAD2 * KP * 2);

    hipMemsetAsync(zbase, 0, zspan, stream);
    hipLaunchKernelGGL(deg_cnt_kernel,     dim3(625),       dim3(256), 0, stream, ei, ew, deg, cnt, mask, flags);
    hipLaunchKernelGGL(partial_w2t_kernel, dim3(NBLK+1024), dim3(256), 0, stream, cnt, deg, mask, flags, mtmp, dinv, bcnt, bmsk, W2, W2t, logitsC);
    hipLaunchKernelGGL(apply_kernel,       dim3(NBLK),      dim3(256), 0, stream, cnt, mtmp, bcnt, bmsk, batch, offs, perm, bc, nmp, cursor, out);
    hipLaunchKernelGGL(scatter_kernel,     dim3(625),       dim3(256), 0, stream, ei, ew, dinv, offs, cursor, ssrc, snorm);
    hipLaunchKernelGGL(axf_kernel,         dim3(79),        dim3(256), 0, stream, x, ssrc, snorm, offs, cnt, dinv, Axf);
    hipLaunchKernelGGL(aggW1_kernel,       dim3(MPAD2/2),   dim3(256), 0, stream, Axf, W1, b1, ssrc, snorm, offs, cnt, dinv, perm, nmp, G);
    hipLaunchKernelGGL(gemm_kernel,        dim3(MT2*8),     dim3(256), 0, stream, G, W2t, b2, Wf, nmp, logitsC);
    hipLaunchKernelGGL(softmax_kernel,     dim3(NG),        dim3(256), 0, stream, logitsC, perm, bc, nmp, out);
}

// Round 12
// 197.496 us; speedup vs baseline: 1.0824x; 1.0052x over previous
//
#include <hip/hip_runtime.h>

#define NN 20000
#define NE 160000
#define NG 16
#define KP 1024            // padded feature dim
#define MT2 160            // max M strips of 128 in compact space
#define MPAD2 (MT2*128)    // 20480
#define NBLK 79            // ceil(20000/256)

typedef __attribute__((ext_vector_type(8))) short bf16x8;
typedef __attribute__((ext_vector_type(4))) float f32x4;

#define GAS __attribute__((address_space(1)))
#define LAS __attribute__((address_space(3)))

__device__ __forceinline__ unsigned short f2bf(float f) {
    unsigned int u = __float_as_uint(f);
    u += 0x7FFFu + ((u >> 16) & 1u);   // round-to-nearest-even
    return (unsigned short)(u >> 16);
}

__device__ __forceinline__ void gld_lds16(const char* g, char* l) {
    __builtin_amdgcn_global_load_lds((GAS void*)g, (LAS void*)l, 16, 0, 0);
}

// deg/cnt/flags zeroed by hipMemsetAsync before this.
// Also probes the mask bit-format (int32 {0,1} / float32 {0,1.0f} / byte).
__global__ void deg_cnt_kernel(const int* __restrict__ ei, const float* __restrict__ ew,
                               float* deg, int* cnt, const void* __restrict__ mask,
                               int* flags) {
    const int e = blockIdx.x * blockDim.x + threadIdx.x;
    if (e < 5000) {
        const unsigned v = ((const unsigned*)mask)[e];
        if (v > 1u) atomicOr(&flags[0], 1);                      // not int32 {0,1}
        if (v != 0u && v != 0x3F800000u) atomicOr(&flags[1], 1); // not float32 {0,1.0f}
    }
    if (e >= NE) return;
    const int c = ei[NE + e];
    atomicAdd(&deg[c], ew[e]);
    atomicAdd(&cnt[c], 1);
}

// blocks 0..NBLK-1: per-block sums (edge counts + mask), dinv, mask decode.
// blocks NBLK..NBLK+1023: W2t[n][k] = bf16(W2[k][n]) zero-padded, + zero logitsC.
__global__ __launch_bounds__(256) void partial_w2t_kernel(const int* __restrict__ cnt,
        const float* __restrict__ deg, const void* __restrict__ mask,
        const int* __restrict__ flags, int* __restrict__ mtmp,
        float* __restrict__ dinv, int* __restrict__ bcnt, int* __restrict__ bmsk,
        const float* __restrict__ W2, unsigned short* __restrict__ W2t,
        float* __restrict__ logitsC) {
    const int bid = blockIdx.x;
    const int t = threadIdx.x;
    if (bid < NBLK) {
        const int i = bid * 256 + t;
        const int f0 = flags[0], f1 = flags[1];
        int c = 0, mv = 0;
        if (i < NN) {
            c = cnt[i];
            dinv[i] = 1.0f / sqrtf(2.0f + deg[i]);   // self-loop weight 2 folded; > 0
            if (f0 == 0)      mv = ((const int*)mask)[i] != 0;
            else if (f1 == 0) mv = ((const unsigned*)mask)[i] != 0u;
            else              mv = ((const unsigned char*)mask)[i] != 0;
            mtmp[i] = mv;
        }
        __shared__ int sc[256], sm[256];
        sc[t] = c; sm[t] = mv;
        __syncthreads();
        for (int off = 128; off; off >>= 1) {
            if (t < off) { sc[t] += sc[t + off]; sm[t] += sm[t + off]; }
            __syncthreads();
        }
        if (t == 0) { bcnt[bid] = sc[0]; bmsk[bid] = sm[0]; }
    } else {
        __shared__ float tile[32][33];
        const int bw = bid - NBLK;
        if (t < 20) logitsC[bw * 20 + t] = 0.0f;   // 1024*20 == 20480 == MPAD2
        const int n0 = (bw & 31) * 32;
        const int k0 = (bw >> 5) * 32;
        const int tx = t & 31, ty = t >> 5;        // 32 x 8
#pragma unroll
        for (int j = 0; j < 4; ++j) {
            const int k = k0 + ty + j * 8;
            const int n = n0 + tx;
            tile[ty + j * 8][tx] = (k < 1000 && n < 1000) ? W2[k * 1000 + n] : 0.0f;
        }
        __syncthreads();
#pragma unroll
        for (int j = 0; j < 4; ++j) {
            const int n = n0 + ty + j * 8;
            const int k = k0 + tx;
            W2t[(size_t)n * KP + k] = f2bf(tile[tx][ty + j * 8]);
        }
    }
}

// apply: re-scan the NBLK partials in-block, then in-block scan + offsets ->
// offs, perm, bc; block 0 writes nm. Also zeroes cursor (pre-scatter) and
// out (pre-softmax; unmasked slots must be 0).
__global__ __launch_bounds__(256) void apply_kernel(const int* __restrict__ cnt,
        const int* __restrict__ mtmp, const int* __restrict__ bcnt,
        const int* __restrict__ bmsk, const int* __restrict__ batch,
        int* __restrict__ offs, int* __restrict__ perm, int* __restrict__ bc,
        int* __restrict__ nm, int* __restrict__ cursor, float* __restrict__ out) {
    const int b = blockIdx.x, t = threadIdx.x;
    __shared__ int pbc[128], pbm[128];
    if (t < 128) {
        pbc[t] = (t < NBLK) ? bcnt[t] : 0;
        pbm[t] = (t < NBLK) ? bmsk[t] : 0;
    }
    __syncthreads();
    for (int off = 1; off < 128; off <<= 1) {       // inclusive scan of partials
        int uc = 0, um = 0;
        if (t < 128 && t >= off) { uc = pbc[t - off]; um = pbm[t - off]; }
        __syncthreads();
        if (t < 128) { pbc[t] += uc; pbm[t] += um; }
        __syncthreads();
    }
    if (b == 0 && t == 0) nm[0] = pbm[NBLK - 1];
    const int bco = (b == 0) ? 0 : pbc[b - 1];      // exclusive block offsets
    const int bmo = (b == 0) ? 0 : pbm[b - 1];
    const int i = b * 256 + t;
    const int c  = (i < NN) ? cnt[i]  : 0;
    const int mv = (i < NN) ? mtmp[i] : 0;
    __shared__ int sc[256], sm[256];
    sc[t] = c; sm[t] = mv;
    __syncthreads();
    for (int off = 1; off < 256; off <<= 1) {
        const int uc = (t >= off) ? sc[t - off] : 0;
        const int um = (t >= off) ? sm[t - off] : 0;
        __syncthreads();
        sc[t] += uc; sm[t] += um;
        __syncthreads();
    }
    if (i < NN) {
        cursor[i] = 0;
        out[i] = 0.0f;
        offs[i] = bco + sc[t] - c;                  // exclusive edge-count prefix
        if (mv) {
            const int pos = bmo + sm[t] - 1;        // compact slot
            perm[pos] = i;
            bc[pos] = batch[i];
        }
    }
}

__global__ void scatter_kernel(const int* __restrict__ ei, const float* __restrict__ ew,
                               const float* __restrict__ dinv, const int* __restrict__ offs,
                               int* cursor, int* __restrict__ ssrc, float* __restrict__ snorm) {
    const int e = blockIdx.x * blockDim.x + threadIdx.x;
    if (e >= NE) return;
    const int r = ei[e], c = ei[NE + e];
    const int pos = atomicAdd(&cursor[c], 1);
    const int idx = offs[c] + pos;
    ssrc[idx] = r;
    snorm[idx] = dinv[r] * ew[e] * dinv[c];
}

// Axf = full first-layer aggregation incl. self-loop
__global__ __launch_bounds__(256) void axf_kernel(const float* __restrict__ x,
        const int* __restrict__ ssrc, const float* __restrict__ snorm,
        const int* __restrict__ offs, const int* __restrict__ cnt,
        const float* __restrict__ dinv, float* __restrict__ Axf) {
    const int i = blockIdx.x * blockDim.x + threadIdx.x;
    if (i >= NN) return;
    float a0=0,a1=0,a2=0,a3=0,a4=0;
    const int s0 = offs[i], n = cnt[i];
    for (int e = s0; e < s0 + n; ++e) {
        const int r = ssrc[e];
        const float w = snorm[e];
        const float* xr = x + r * 5;
        a0 += w*xr[0]; a1 += w*xr[1]; a2 += w*xr[2]; a3 += w*xr[3]; a4 += w*xr[4];
    }
    const float wl = 2.0f * dinv[i] * dinv[i];
    const float* xi = x + i * 5;
    a0 += wl*xi[0]; a1 += wl*xi[1]; a2 += wl*xi[2]; a3 += wl*xi[3]; a4 += wl*xi[4];
    float* o = Axf + i * 5;
    o[0]=a0; o[1]=a1; o[2]=a2; o[3]=a3; o[4]=a4;
}

// G[j] = sum_e w_e * relu(Axf[src]@W1 + b1) — h1 never materialized. Barrier-free
// wave-pair structure (R11) + W1 AMORTIZATION (R12): each wave-pair owns 4
// consecutive dests, so the per-wave W1/b1 register fragment (10 KB/wave of L2
// traffic — the R11 residue, ~500 MB total at 2 dests/block) is loaded once per
// 4 dests (~50 MB total). Dest metadata prefetched in two batched rounds.
// Edge values broadcast via __shfl; no LDS, no __syncthreads.
__global__ __launch_bounds__(256) void aggW1_kernel(const float* __restrict__ Axf,
        const float* __restrict__ W1, const float* __restrict__ b1,
        const int* __restrict__ ssrc, const float* __restrict__ snorm,
        const int* __restrict__ offs, const int* __restrict__ cnt,
        const float* __restrict__ dinv, const int* __restrict__ perm,
        const int* __restrict__ nm, unsigned short* __restrict__ G) {
    const int tid = threadIdx.x;
    const int wv = tid >> 6;
    const int lane = tid & 63;
    const int half = wv & 1;
    const int jbase = blockIdx.x * 8 + (wv >> 1) * 4;   // wave-pair -> 4 dests
    const int nmv = nm[0];
    const int npad = (nmv + 127) & ~127;
    if (jbase >= npad) return;        // wave-uniform (no barriers in this kernel)

    const int c0 = half * 512 + lane * 8;
    float w1r[5][8], bbr[8];
#pragma unroll
    for (int q = 0; q < 2; ++q) {
        const int c = c0 + q * 4;
        const bool v = (c <= 996);    // 1000 % 4 == 0: quads are all-valid or all-pad
#pragma unroll
        for (int f = 0; f < 5; ++f) {
            const float4 w4 = v ? *(const float4*)(W1 + f * 1000 + c)
                                : make_float4(0.f, 0.f, 0.f, 0.f);
            w1r[f][q*4+0] = w4.x; w1r[f][q*4+1] = w4.y;
            w1r[f][q*4+2] = w4.z; w1r[f][q*4+3] = w4.w;
        }
        const float4 b4 = v ? *(const float4*)(b1 + c) : make_float4(0.f, 0.f, 0.f, 0.f);
        bbr[q*4+0] = b4.x; bbr[q*4+1] = b4.y; bbr[q*4+2] = b4.z; bbr[q*4+3] = b4.w;
    }

    // prefetch the 4 dests' metadata (two batched rounds -> latency pipelined)
    int iv[4], s0a[4], na[4]; float dva[4];
#pragma unroll
    for (int d = 0; d < 4; ++d) {
        const int j = jbase + d;                 // j < npad (npad is a mult of 8)
        iv[d] = (j < nmv) ? perm[j] : -1;
    }
#pragma unroll
    for (int d = 0; d < 4; ++d) {
        if (iv[d] >= 0) { s0a[d] = offs[iv[d]]; na[d] = cnt[iv[d]]; dva[d] = dinv[iv[d]]; }
        else            { s0a[d] = 0; na[d] = -1; dva[d] = 0.f; }
    }

#pragma unroll
    for (int d = 0; d < 4; ++d) {
        const int j = jbase + d;
        float acc[8];
#pragma unroll
        for (int k = 0; k < 8; ++k) acc[k] = 0.f;
        const int i = iv[d];
        if (i >= 0) {                            // wave-uniform
            const int s0 = s0a[d], n = na[d];
            const int total = n + 1;             // + self-loop pseudo-edge
            for (int base = 0; base < total; base += 64) {
                const int m = (total - base < 64) ? (total - base) : 64;
                float a0=0.f, a1=0.f, a2=0.f, a3=0.f, a4=0.f, we=0.f;
                if (lane < m) {
                    const int idx = base + lane;
                    int r;
                    if (idx < n) { r = ssrc[s0 + idx]; we = snorm[s0 + idx]; }
                    else         { r = i; we = 2.0f * dva[d] * dva[d]; }
                    const float* axr = Axf + r * 5;
                    a0 = axr[0]; a1 = axr[1]; a2 = axr[2]; a3 = axr[3]; a4 = axr[4];
                }
#pragma unroll 2
                for (int e = 0; e < m; ++e) {
                    const float s0v = __shfl(a0, e);
                    const float s1v = __shfl(a1, e);
                    const float s2v = __shfl(a2, e);
                    const float s3v = __shfl(a3, e);
                    const float s4v = __shfl(a4, e);
                    const float swv = __shfl(we, e);
#pragma unroll
                    for (int k = 0; k < 8; ++k) {
                        const float z = bbr[k] + s0v * w1r[0][k] + s1v * w1r[1][k]
                                      + s2v * w1r[2][k] + s3v * w1r[3][k] + s4v * w1r[4][k];
                        acc[k] += swv * fmaxf(z, 0.f);
                    }
                }
            }
        }
        bf16x8 pk;
#pragma unroll
        for (int k = 0; k < 8; ++k) pk[k] = (short)f2bf(acc[k]);
        *(bf16x8*)(G + (size_t)j * KP + c0) = pk;
    }
}

// logitsC[row] += sum_cols relu(G @ W2 + b2) * Wf over compact rows < nm.
// 128x128 tile / BK=32 / width-16 global_load_lds / XOR-swizzled LDS.
// tm=(bid>>6)*8+(bid&7), tn=(bid>>3)&7: id%8==tm%8 -> A-strip's 8 readers share
// an XCD (FETCH 163->33 MB measured R6). Blocks with tm >= active strips exit.
__global__ __launch_bounds__(256) void gemm_kernel(const unsigned short* __restrict__ A,
                                                   const unsigned short* __restrict__ B,
                                                   const float* __restrict__ b2,
                                                   const float* __restrict__ Wf,
                                                   const int* __restrict__ nm,
                                                   float* __restrict__ logitsC) {
    __shared__ unsigned short As[4096];  // 128 rows x 32 k (bf16) = 8 KB
    __shared__ unsigned short Bs[4096];
    const int tid = threadIdx.x;
    __shared__ int s_nm;
    if (tid == 0) s_nm = nm[0];
    __syncthreads();
    const int nmv = s_nm;
    const int mstrips = (nmv + 127) >> 7;
    const int bid = blockIdx.x;
    const int tm = (bid >> 6) * 8 + (bid & 7);   // 0..159, tm%8 == bid%8
    const int tn = (bid >> 3) & 7;
    if (tm >= mstrips) return;
    const int lane = tid & 63;
    const int wv = tid >> 6;
    const int wr = wv >> 1, wc = wv & 1;

    const int chunk = ((tid & 3) ^ ((tid >> 3) & 3)) * 16;
    const int rsub = tid >> 2;   // row 0..63 (+64 in round 1)
    const char* Ag = (const char*)(A + (size_t)(tm * 128 + rsub) * KP) + chunk;
    const char* Bg = (const char*)(B + (size_t)(tn * 128 + rsub) * KP) + chunk;
    char* AsW = (char*)As + wv * 1024;
    char* BsW = (char*)Bs + wv * 1024;

    f32x4 acc[4][4];
#pragma unroll
    for (int i = 0; i < 4; ++i)
#pragma unroll
        for (int j = 0; j < 4; ++j) acc[i][j] = (f32x4){0.f, 0.f, 0.f, 0.f};

    const int m = lane & 15;
    const int quad = lane >> 4;
    const int sw = quad ^ ((m >> 1) & 3);       // swizzled k-chunk slot
    const int aoff = (wr * 64 + m) * 64 + sw * 16;
    const int boff = (wc * 64 + m) * 64 + sw * 16;

    for (int kk = 0; kk < KP; kk += 32) {
        __syncthreads();
        const int kb = kk * 2;
        gld_lds16(Ag + kb,             AsW);
        gld_lds16(Ag + kb + 64 * 2048, AsW + 4096);
        gld_lds16(Bg + kb,             BsW);
        gld_lds16(Bg + kb + 64 * 2048, BsW + 4096);
        __syncthreads();
        bf16x8 af[4], bfv[4];
#pragma unroll
        for (int mt = 0; mt < 4; ++mt)
            af[mt] = *(const bf16x8*)((const char*)As + aoff + mt * 1024);
#pragma unroll
        for (int nt = 0; nt < 4; ++nt)
            bfv[nt] = *(const bf16x8*)((const char*)Bs + boff + nt * 1024);
#pragma unroll
        for (int mt = 0; mt < 4; ++mt)
#pragma unroll
            for (int nt = 0; nt < 4; ++nt)
                acc[mt][nt] = __builtin_amdgcn_mfma_f32_16x16x32_bf16(af[mt], bfv[nt], acc[mt][nt], 0, 0, 0);
    }

    // epilogue: C/D layout col = lane&15, row = quad*4 + reg
    const int col0 = tn * 128 + wc * 64 + m;
    const int row00 = tm * 128 + wr * 64 + quad * 4;
#pragma unroll
    for (int mt = 0; mt < 4; ++mt) {
        float ps0 = 0.f, ps1 = 0.f, ps2 = 0.f, ps3 = 0.f;
#pragma unroll
        for (int nt = 0; nt < 4; ++nt) {
            const int c = col0 + nt * 16;
            const float bbv = (c < 1000) ? b2[c] : 0.0f;
            const float wfv = (c < 1000) ? Wf[c] : 0.0f;
            ps0 += fmaxf(acc[mt][nt][0] + bbv, 0.f) * wfv;
            ps1 += fmaxf(acc[mt][nt][1] + bbv, 0.f) * wfv;
            ps2 += fmaxf(acc[mt][nt][2] + bbv, 0.f) * wfv;
            ps3 += fmaxf(acc[mt][nt][3] + bbv, 0.f) * wfv;
        }
#pragma unroll
        for (int msk = 1; msk < 16; msk <<= 1) {
            ps0 += __shfl_xor(ps0, msk);
            ps1 += __shfl_xor(ps1, msk);
            ps2 += __shfl_xor(ps2, msk);
            ps3 += __shfl_xor(ps3, msk);
        }
        if (m == 0) {
            const int row = row00 + mt * 16;
            if (row + 0 < nmv) atomicAdd(&logitsC[row + 0], ps0);
            if (row + 1 < nmv) atomicAdd(&logitsC[row + 1], ps1);
            if (row + 2 < nmv) atomicAdd(&logitsC[row + 2], ps2);
            if (row + 3 < nmv) atomicAdd(&logitsC[row + 3], ps3);
        }
    }
}

// segment softmax over compact (all-masked) logits; bc sorted -> binary search.
// out pre-zeroed by apply_kernel; only masked slots written via perm.
__global__ __launch_bounds__(256) void softmax_kernel(const float* __restrict__ logitsC,
        const int* __restrict__ perm, const int* __restrict__ bc,
        const int* __restrict__ nm, float* __restrict__ out) {
    const int g = blockIdx.x;
    const int t = threadIdx.x;
    __shared__ int s_lo, s_hi;
    __shared__ float red[4];
    __shared__ float sval;
    if (t == 0) {
        const int nmv = nm[0];
        int lo = 0, hi = nmv;
        while (lo < hi) { const int mid = (lo + hi) >> 1; if (bc[mid] < g) lo = mid + 1; else hi = mid; }
        s_lo = lo;
        int lo2 = lo, hi2 = nmv;
        while (lo2 < hi2) { const int mid = (lo2 + hi2) >> 1; if (bc[mid] < g + 1) lo2 = mid + 1; else hi2 = mid; }
        s_hi = lo2;
    }
    __syncthreads();
    const int lo = s_lo, hi = s_hi;
    float mx = -1e30f;
    for (int i = lo + t; i < hi; i += 256) mx = fmaxf(mx, logitsC[i]);
    for (int off = 32; off; off >>= 1) mx = fmaxf(mx, __shfl_down(mx, off));
    if ((t & 63) == 0) red[t >> 6] = mx;
    __syncthreads();
    if (t == 0) sval = fmaxf(fmaxf(red[0], red[1]), fmaxf(red[2], red[3]));
    __syncthreads();
    mx = sval;
    __syncthreads();
    float sm = 0.f;
    for (int i = lo + t; i < hi; i += 256) sm += expf(logitsC[i] - mx);
    for (int off = 32; off; off >>= 1) sm += __shfl_down(sm, off);
    if ((t & 63) == 0) red[t >> 6] = sm;
    __syncthreads();
    if (t == 0) sval = red[0] + red[1] + red[2] + red[3];
    __syncthreads();
    const float inv = 1.0f / fmaxf(sval, 1e-16f);
    for (int i = lo + t; i < hi; i += 256)
        out[perm[i]] = expf(logitsC[i] - mx) * inv;
}

extern "C" void kernel_launch(void* const* d_in, const int* in_sizes, int n_in,
                              void* d_out, int out_size, void* d_ws, size_t ws_size,
                              hipStream_t stream) {
    (void)in_sizes; (void)n_in; (void)out_size; (void)ws_size;
    const float* x   = (const float*)d_in[0];
    const float* ew  = (const float*)d_in[1];
    const float* W1  = (const float*)d_in[2];
    const float* b1  = (const float*)d_in[3];
    const float* W2  = (const float*)d_in[4];
    const float* b2  = (const float*)d_in[5];
    const float* Wf  = (const float*)d_in[6];
    const int*   ei  = (const int*)d_in[8];
    const void*  mask  = d_in[9];
    const int*   batch = (const int*)d_in[10];
    float* out = (float*)d_out;

    char* p = (char*)d_ws;
    auto carve = [&](size_t bytes) { char* q = p; p += (bytes + 255) & ~(size_t)255; return q; };
    // zero-region (single hipMemsetAsync): deg, cnt, flags only
    char* zbase = p;
    float* deg     = (float*)carve(NN * 4);
    int*   cnt     = (int*)carve(NN * 4);
    int*   flags   = (int*)carve(256);
    size_t zspan = (size_t)(p - zbase);
    int*   cursor  = (int*)carve(NN * 4);
    float* logitsC = (float*)carve(MPAD2 * 4);
    int*   offs   = (int*)carve(NN * 4);
    float* dinv   = (float*)carve(NN * 4);
    int*   mtmp   = (int*)carve(NN * 4);
    int*   perm   = (int*)carve(NN * 4);
    int*   bc     = (int*)carve(NN * 4);
    int*   bcnt   = (int*)carve(NBLK * 4);
    int*   bmsk   = (int*)carve(NBLK * 4);
    int*   nmp    = (int*)carve(256);
    int*   ssrc   = (int*)carve(NE * 4);
    float* snorm  = (float*)carve(NE * 4);
    float* Axf    = (float*)carve(NN * 5 * 4);
    unsigned short* W2t = (unsigned short*)carve((size_t)KP * KP * 2);
    unsigned short* G   = (unsigned short*)carve((size_t)MPAD2 * KP * 2);

    hipMemsetAsync(zbase, 0, zspan, stream);
    hipLaunchKernelGGL(deg_cnt_kernel,     dim3(625),       dim3(256), 0, stream, ei, ew, deg, cnt, mask, flags);
    hipLaunchKernelGGL(partial_w2t_kernel, dim3(NBLK+1024), dim3(256), 0, stream, cnt, deg, mask, flags, mtmp, dinv, bcnt, bmsk, W2, W2t, logitsC);
    hipLaunchKernelGGL(apply_kernel,       dim3(NBLK),      dim3(256), 0, stream, cnt, mtmp, bcnt, bmsk, batch, offs, perm, bc, nmp, cursor, out);
    hipLaunchKernelGGL(scatter_kernel,     dim3(625),       dim3(256), 0, stream, ei, ew, dinv, offs, cursor, ssrc, snorm);
    hipLaunchKernelGGL(axf_kernel,         dim3(79),        dim3(256), 0, stream, x, ssrc, snorm, offs, cnt, dinv, Axf);
    hipLaunchKernelGGL(aggW1_kernel,       dim3(MPAD2/8),   dim3(256), 0, stream, Axf, W1, b1, ssrc, snorm, offs, cnt, dinv, perm, nmp, G);
    hipLaunchKernelGGL(gemm_kernel,        dim3(MT2*8),     dim3(256), 0, stream, G, W2t, b2, Wf, nmp, logitsC);
    hipLaunchKernelGGL(softmax_kernel,     dim3(NG),        dim3(256), 0, stream, logitsC, perm, bc, nmp, out);
}